// Round 2
// baseline (317.380 us; speedup 1.0000x reference)
//
#include <hip/hip_runtime.h>
#include <stdint.h>

// Inv2d fused pipeline, MI355X gfx950.
// B=16, C=256, H=W=64, K2=9. All inputs fp32; internal GEMMs in bf16 MFMA.
//
// ws layout:
//   Wr/Wn (bf16, tiled [b][slab=c/32][p][c%32])  : 33,554,432 B
//   w_reduce bf16 tiled [ks][o][32]              :    131,072 B
//   w_span  bf16 tiled [ks][mt][phys=k2*16+g][32]:  1,179,648 B
//   stats partials [s][k][j][2] f32              :    131,072 B
//   coeffs [c][2] f32 (A=gamma*rstd, B=beta-mean*A):     2,048 B

typedef __attribute__((ext_vector_type(4))) float f32x4;
typedef __attribute__((ext_vector_type(8))) short s16x8;
typedef __attribute__((ext_vector_type(8))) __bf16 bf16x8;

__device__ __forceinline__ float bf2f(uint16_t u){
  union { uint32_t i; float f; } v; v.i = ((uint32_t)u) << 16; return v.f;
}
__device__ __forceinline__ uint16_t f2bf(float f){
  union { float f; uint32_t i; } v; v.f = f;
  return (uint16_t)((v.i + 0x7fffu + ((v.i >> 16) & 1u)) >> 16);  // RNE
}

// SFINAE shim: prefer short8 operands (guide-verified); fall back to __bf16 vec.
template <typename V>
__device__ __forceinline__ auto mfma16x16x32(V a, V b, f32x4 c, int)
    -> decltype(__builtin_amdgcn_mfma_f32_16x16x32_bf16(a, b, c, 0, 0, 0)) {
  return __builtin_amdgcn_mfma_f32_16x16x32_bf16(a, b, c, 0, 0, 0);
}
template <typename V>
__device__ __forceinline__ f32x4 mfma16x16x32(V a, V b, f32x4 c, long) {
  bf16x8 aa = __builtin_bit_cast(bf16x8, a);
  bf16x8 bb = __builtin_bit_cast(bf16x8, b);
  return __builtin_amdgcn_mfma_f32_16x16x32_bf16(aa, bb, c, 0, 0, 0);
}

typedef uint32_t u32_g __attribute__((address_space(1)));
typedef uint32_t u32_l __attribute__((address_space(3)));
__device__ __forceinline__ void glds16(const void* g, void* l){
  // lds dest is wave-uniform base + lane*16; global src is per-lane.
  __builtin_amdgcn_global_load_lds((const u32_g*)g, (u32_l*)l, 16, 0, 0);
}

// ---------------- kernel 0: weight convert + pre-tile ----------------
__global__ __launch_bounds__(256) void prep_weights(
    const float* __restrict__ wred, const float* __restrict__ wsp,
    uint16_t* __restrict__ wrt, uint16_t* __restrict__ wspt){
  int id = blockIdx.x * 256 + threadIdx.x;   // 16B-chunk id, 320*256 = 81920 total
  union { uint4 v; uint16_t h[8]; } u;
  if (id < 8192){                            // w_reduce: [ks][o][32]
    int ks = id >> 10;
    int o  = (id >> 2) & 255;
    int j0 = (id & 3) * 8;
    const float* s = wred + o * 256 + ks * 32 + j0;
    #pragma unroll
    for (int i = 0; i < 8; i++) u.h[i] = f2bf(s[i]);
    *(uint4*)(wrt + ((size_t)(ks * 256 + o) * 32 + j0)) = u.v;
  } else {                                   // w_span: [ks][mt][phys][32], phys=k2*16+g
    int c16 = id - 8192;                     // < 73728
    int j0  = (c16 & 3) * 8;
    int row = c16 >> 2;                      // < 18432
    int phys = row % 144;
    int mtks = row / 144;                    // ks*16 + mt
    int mt = mtks & 15, ks = mtks >> 4;
    int g = phys & 15, k2 = phys >> 4;
    int sg = mt * 144 + g * 9 + k2;          // s = (mt*16+g)*9 + k2
    const float* s = wsp + (size_t)sg * 256 + ks * 32 + j0;
    #pragma unroll
    for (int i = 0; i < 8; i++) u.h[i] = f2bf(s[i]);
    *(uint4*)(wspt + ((size_t)row * 32 + j0)) = u.v;
  }
}

// ---------------- kernel 1: Wr = w_reduce @ X + b_reduce (bf16 out, tiled) ----------------
__global__ __launch_bounds__(256) void k1_reduce_gemm(
    const float* __restrict__ X, const uint16_t* __restrict__ wrt,
    const float* __restrict__ bred, uint16_t* __restrict__ Wr){
  const int pt = blockIdx.x, mt = blockIdx.y, b = blockIdx.z;
  const int p0 = pt * 128, o0 = mt * 128;
  __shared__ __align__(16) uint16_t Al[2][128*32];
  __shared__ __align__(16) uint16_t Bl[2][128*32];
  const int t = threadIdx.x;
  const int wv = t >> 6, lane = t & 63, q = lane >> 4, l = lane & 15;
  const int wm = wv >> 1, wn = wv & 1;
  const int c2 = (t & 15) * 2, seg = t >> 4;
  f32x4 acc[4][4] = {};
  union { float f[8]; float4 v[2]; } v0, v1;

  auto stageA = [&](int ks, int buf){
    const char* src = (const char*)(wrt + ((size_t)ks * 256 + o0) * 32);
    char* dst = (char*)(&Al[buf][0]);
    for (int cc = wv; cc < 8; cc += 4)
      glds16(src + cc*1024 + lane*16, dst + cc*1024);
  };
  auto loadB = [&](int ks){
    const float* s0 = X + ((size_t)(b * 256 + ks * 32 + c2)) * 4096 + p0 + seg * 8;
    const float* s1 = s0 + 4096;
    v0.v[0] = *(const float4*)(s0 + 0);
    v0.v[1] = *(const float4*)(s0 + 4);
    v1.v[0] = *(const float4*)(s1 + 0);
    v1.v[1] = *(const float4*)(s1 + 4);
  };
  auto writeB = [&](int buf){
    uint16_t* dst = &Bl[buf][(seg * 8) * 32 + c2];
    #pragma unroll
    for (int i = 0; i < 8; i++){
      uint32_t pk = (uint32_t)f2bf(v0.f[i]) | ((uint32_t)f2bf(v1.f[i]) << 16);
      *(uint32_t*)(dst + (size_t)i * 32) = pk;
    }
  };

  stageA(0, 0); loadB(0); writeB(0);
  __syncthreads();
  int cur = 0;
  for (int ks = 0; ks < 8; ks++){
    if (ks < 7){ stageA(ks + 1, cur ^ 1); loadB(ks + 1); }
    s16x8 af[4], bfv[4];
    #pragma unroll
    for (int mi = 0; mi < 4; mi++)
      af[mi] = *(const s16x8*)(&Al[cur][(wm*64 + mi*16 + l)*32 + q*8]);
    #pragma unroll
    for (int ni = 0; ni < 4; ni++)
      bfv[ni] = *(const s16x8*)(&Bl[cur][(wn*64 + ni*16 + l)*32 + q*8]);
    #pragma unroll
    for (int mi = 0; mi < 4; mi++)
      #pragma unroll
      for (int ni = 0; ni < 4; ni++)
        acc[mi][ni] = mfma16x16x32(af[mi], bfv[ni], acc[mi][ni], 0);
    if (ks < 7) writeB(cur ^ 1);
    __syncthreads();
    cur ^= 1;
  }
  // epilogue: +b_reduce, bf16, store tiled [b][o/32][p][o%32]
  #pragma unroll
  for (int mi = 0; mi < 4; mi++){
    int o = o0 + wm*64 + mi*16 + q*4;
    float4 br = *(const float4*)(bred + o);
    int slab = o >> 5, orem = o & 31;
    #pragma unroll
    for (int ni = 0; ni < 4; ni++){
      int p = p0 + wn*64 + ni*16 + l;
      f32x4 v = acc[mi][ni];
      uint32_t lo = (uint32_t)f2bf(v[0] + br.x) | ((uint32_t)f2bf(v[1] + br.y) << 16);
      uint32_t hi = (uint32_t)f2bf(v[2] + br.z) | ((uint32_t)f2bf(v[3] + br.w) << 16);
      uint2 pk; pk.x = lo; pk.y = hi;
      *(uint2*)(Wr + ((size_t)((b*8 + slab)*4096 + p)) * 32 + orem) = pk;
    }
  }
}

// ---------------- kernel 2a: per-channel partial sums (deterministic) ----------------
__global__ __launch_bounds__(256) void bn_stats(const uint16_t* __restrict__ Wr,
                                                float* __restrict__ part){
  const int s = blockIdx.y, k = blockIdx.x, t = threadIdx.x;
  const int j = t & 31, gsub = t >> 5;
  float sum = 0.f, sq = 0.f;
  const int rbase = k * 1024 + gsub;
  for (int i = 0; i < 128; i++){
    int r = rbase + i * 8;                 // r in [0,65536): (b=r>>12, p=r&4095)
    int bb = r >> 12, p = r & 4095;
    float v = bf2f(Wr[((size_t)((bb * 8 + s) * 4096) + p) * 32 + j]);
    sum += v; sq += v * v;
  }
  __shared__ float ls[8][32][2];
  ls[gsub][j][0] = sum; ls[gsub][j][1] = sq;
  __syncthreads();
  if (t < 32){
    float a = 0.f, b2 = 0.f;
    for (int g2 = 0; g2 < 8; g2++){ a += ls[g2][t][0]; b2 += ls[g2][t][1]; }
    float* dst = part + ((size_t)(s * 64 + k) * 32 + t) * 2;
    dst[0] = a; dst[1] = b2;
  }
}

// ---------------- kernel 2b: finalize BN coeffs ----------------
__global__ void bn_final(const float* __restrict__ part, const float* __restrict__ gamma,
                         const float* __restrict__ beta, float* __restrict__ coeffs){
  int c = threadIdx.x;
  int s = c >> 5, j = c & 31;
  float sum = 0.f, sq = 0.f;
  for (int k = 0; k < 64; k++){
    const float* p = part + ((size_t)(s * 64 + k) * 32 + j) * 2;
    sum += p[0]; sq += p[1];
  }
  const float inv = 1.0f / 65536.0f;
  float mean = sum * inv;
  float var  = sq * inv - mean * mean;
  float rstd = rsqrtf(var + 1e-5f);
  float A = gamma[c] * rstd;
  float Bc = beta[c] - mean * A;
  coeffs[2*c] = A; coeffs[2*c+1] = Bc;
}

// ---------------- kernel 2c: Wn = relu(Wr*A + B) in-place ----------------
// Wr = 2^25 B = 2,097,152 16B-chunks. 1024 blocks x 256 thr x 8 iters = exact cover.
__global__ __launch_bounds__(256) void bn_apply(uint16_t* __restrict__ Wr,
                                                const float* __restrict__ coeffs){
  __shared__ float cf[512];
  cf[threadIdx.x]       = coeffs[threadIdx.x];
  cf[threadIdx.x + 256] = coeffs[threadIdx.x + 256];
  __syncthreads();
  for (int it = 0; it < 8; it++){
    size_t c16 = (size_t)blockIdx.x * 256 + threadIdx.x + (size_t)it * (1024u*256u);
    uint16_t* pch = Wr + c16 * 8;
    int sj = (int)((c16 >> 14) & 7);       // slab (16384 chunks per (b,s))
    int j0 = (int)(c16 & 3) * 8;
    union { uint4 v; uint16_t h[8]; } u;
    u.v = *(const uint4*)pch;
    #pragma unroll
    for (int i = 0; i < 8; i++){
      int cch = sj * 32 + j0 + i;
      float v = bf2f(u.h[i]);
      v = fmaf(v, cf[2*cch], cf[2*cch+1]);
      v = fmaxf(v, 0.f);
      u.h[i] = f2bf(v);
    }
    *(uint4*)pch = u.v;
  }
}

// ---------------- kernel 3: Ker = w_span @ Wn + b_span, fused involution ----------------
// Block: M_tile=144 s-rows (16 groups x 9 taps, phys-permuted), N_tile=256 positions,
// 4 waves split N. Lane holds complete 9-tap groups: acc[mi=k2][ni][reg=g_off].
__global__ __launch_bounds__(256) void k3_span_inv(
    const uint16_t* __restrict__ Wn, const uint16_t* __restrict__ wspt,
    const float* __restrict__ bspan, const float* __restrict__ X,
    float* __restrict__ out){
  const int mt = blockIdx.x, pt = blockIdx.y, b = blockIdx.z;
  const int p0 = pt * 256;
  __shared__ __align__(16) uint16_t Al[2][144*32];
  __shared__ __align__(16) uint16_t Bl[2][256*32];
  __shared__ float bsp[144];
  const int t = threadIdx.x;
  const int wv = t >> 6, lane = t & 63, q = lane >> 4, l = lane & 15;
  if (t < 144){
    int g = t & 15, k2 = t >> 4;
    bsp[t] = bspan[mt*144 + g*9 + k2];     // indexed by phys
  }
  f32x4 acc[9][4] = {};
  const char* Abase = (const char*)(wspt + (size_t)mt * (144*32));
  const size_t AslabB = (size_t)16 * 144 * 32 * 2;
  const char* Bbase = (const char*)(Wn + ((size_t)(b * 8) * 4096 + p0) * 32);
  const size_t BslabB = (size_t)4096 * 32 * 2;

  auto stage = [&](int ks, int buf){
    const char* asrc = Abase + (size_t)ks * AslabB;
    char* adst = (char*)(&Al[buf][0]);
    for (int cc = wv; cc < 9; cc += 4)
      glds16(asrc + cc*1024 + lane*16, adst + cc*1024);
    const char* bsrc = Bbase + (size_t)ks * BslabB;
    char* bdst = (char*)(&Bl[buf][0]);
    for (int cc = wv; cc < 16; cc += 4)
      glds16(bsrc + cc*1024 + lane*16, bdst + cc*1024);
  };

  stage(0, 0);
  __syncthreads();
  int cur = 0;
  for (int ks = 0; ks < 8; ks++){
    if (ks < 7) stage(ks + 1, cur ^ 1);
    s16x8 bfv[4];
    #pragma unroll
    for (int ni = 0; ni < 4; ni++)
      bfv[ni] = *(const s16x8*)(&Bl[cur][(wv*64 + ni*16 + l)*32 + q*8]);
    #pragma unroll
    for (int mi = 0; mi < 9; mi++){
      s16x8 af = *(const s16x8*)(&Al[cur][(mi*16 + l)*32 + q*8]);
      #pragma unroll
      for (int ni = 0; ni < 4; ni++)
        acc[mi][ni] = mfma16x16x32(af, bfv[ni], acc[mi][ni], 0);
    }
    __syncthreads();
    cur ^= 1;
  }
  // involution epilogue: out[g][p] = sum_k2 (Ker + b_span) * Xpatch
  const int h = pt*4 + wv;                 // each wave owns one image row
  #pragma unroll
  for (int reg = 0; reg < 4; reg++){
    const int g  = q*4 + reg;
    const int gg = mt*16 + g;
    const float* Xc = X + (size_t)(b*256 + gg) * 4096;
    float bs[9];
    #pragma unroll
    for (int k2 = 0; k2 < 9; k2++) bs[k2] = bsp[k2*16 + g];
    #pragma unroll
    for (int ni = 0; ni < 4; ni++){
      const int wc = ni*16 + l;
      float r = 0.f;
      #pragma unroll
      for (int k2 = 0; k2 < 9; k2++){
        const int dh = k2/3 - 1, dw = k2%3 - 1;
        const int hh = h + dh, ww = wc + dw;
        float xv = (hh >= 0 && hh < 64 && ww >= 0 && ww < 64) ? Xc[hh*64 + ww] : 0.f;
        r += (acc[k2][ni][reg] + bs[k2]) * xv;
      }
      out[((size_t)(b*256 + gg) * 64 + h) * 64 + wc] = r;
    }
  }
}

extern "C" void kernel_launch(void* const* d_in, const int* in_sizes, int n_in,
                              void* d_out, int out_size, void* d_ws, size_t ws_size,
                              hipStream_t stream) {
  const float* X     = (const float*)d_in[0];
  const float* wred  = (const float*)d_in[1];
  const float* bred  = (const float*)d_in[2];
  const float* gamma = (const float*)d_in[3];
  const float* beta  = (const float*)d_in[4];
  const float* wsp   = (const float*)d_in[5];
  const float* bsp   = (const float*)d_in[6];
  float* out = (float*)d_out;

  char* ws = (char*)d_ws;
  uint16_t* Wr   = (uint16_t*)(ws);
  uint16_t* wrt  = (uint16_t*)(ws + 33554432);
  uint16_t* wspt = (uint16_t*)(ws + 33554432 + 131072);
  float* part    = (float*)(ws + 33554432 + 131072 + 1179648);
  float* coeffs  = (float*)(ws + 33554432 + 131072 + 1179648 + 131072);
  if (ws_size < (size_t)(33554432 + 131072 + 1179648 + 131072 + 2048)) return;

  prep_weights<<<320, 256, 0, stream>>>(wred, wsp, wrt, wspt);
  k1_reduce_gemm<<<dim3(32, 2, 16), 256, 0, stream>>>(X, wrt, bred, Wr);
  bn_stats<<<dim3(64, 8), 256, 0, stream>>>(Wr, part);
  bn_final<<<1, 256, 0, stream>>>(part, gamma, beta, coeffs);
  bn_apply<<<1024, 256, 0, stream>>>(Wr, coeffs);
  k3_span_inv<<<dim3(16, 16, 16), 256, 0, stream>>>(Wr, wspt, bsp, X, out);
}

// Round 3
// 187.205 us; speedup vs baseline: 1.6954x; 1.6954x over previous
//
#include <hip/hip_runtime.h>
#include <stdint.h>

// Inv2d fused pipeline, MI355X gfx950.
// B=16, C=256, H=W=64, K2=9. All inputs fp32; internal GEMMs in bf16 MFMA.
//
// ws layout:
//   Wr/Wn (bf16, tiled [b][slab=c/32][p][c%32])  : 33,554,432 B
//   w_reduce bf16 tiled [ks][o][32]              :    131,072 B
//   w_span  bf16 tiled [ks][mt][phys=k2*16+g][32]:  1,179,648 B
//   stats partials [s][k][j][2] f32              :    131,072 B
//   coeffs [c][2] f32 (A=gamma*rstd, B=beta-mean*A):     2,048 B

typedef __attribute__((ext_vector_type(4))) float f32x4;
typedef __attribute__((ext_vector_type(8))) short s16x8;
typedef __attribute__((ext_vector_type(8))) __bf16 bf16x8;

#define WAITV(N) asm volatile("s_waitcnt vmcnt(" #N ")" ::: "memory")
#define WAITL0   asm volatile("s_waitcnt lgkmcnt(0)" ::: "memory")
#define BAR()    do { asm volatile("" ::: "memory"); __builtin_amdgcn_s_barrier(); asm volatile("" ::: "memory"); } while (0)

__device__ __forceinline__ float bf2f(uint16_t u){
  union { uint32_t i; float f; } v; v.i = ((uint32_t)u) << 16; return v.f;
}
__device__ __forceinline__ uint16_t f2bf(float f){
  union { float f; uint32_t i; } v; v.f = f;
  return (uint16_t)((v.i + 0x7fffu + ((v.i >> 16) & 1u)) >> 16);  // RNE
}

// SFINAE shim: prefer short8 operands (guide-verified); fall back to __bf16 vec.
template <typename V>
__device__ __forceinline__ auto mfma16x16x32(V a, V b, f32x4 c, int)
    -> decltype(__builtin_amdgcn_mfma_f32_16x16x32_bf16(a, b, c, 0, 0, 0)) {
  return __builtin_amdgcn_mfma_f32_16x16x32_bf16(a, b, c, 0, 0, 0);
}
template <typename V>
__device__ __forceinline__ f32x4 mfma16x16x32(V a, V b, f32x4 c, long) {
  bf16x8 aa = __builtin_bit_cast(bf16x8, a);
  bf16x8 bb = __builtin_bit_cast(bf16x8, b);
  return __builtin_amdgcn_mfma_f32_16x16x32_bf16(aa, bb, c, 0, 0, 0);
}

typedef uint32_t u32_g __attribute__((address_space(1)));
typedef uint32_t u32_l __attribute__((address_space(3)));
__device__ __forceinline__ void glds16(const void* g, void* l){
  // lds dest is wave-uniform base + lane*16; global src is per-lane.
  __builtin_amdgcn_global_load_lds((const u32_g*)g, (u32_l*)l, 16, 0, 0);
}

// ---------------- kernel 0: weight convert + pre-tile ----------------
__global__ __launch_bounds__(256) void prep_weights(
    const float* __restrict__ wred, const float* __restrict__ wsp,
    uint16_t* __restrict__ wrt, uint16_t* __restrict__ wspt){
  int id = blockIdx.x * 256 + threadIdx.x;   // 16B-chunk id, 320*256 = 81920 total
  union { uint4 v; uint16_t h[8]; } u;
  if (id < 8192){                            // w_reduce: [ks][o][32]
    int ks = id >> 10;
    int o  = (id >> 2) & 255;
    int j0 = (id & 3) * 8;
    const float* s = wred + o * 256 + ks * 32 + j0;
    #pragma unroll
    for (int i = 0; i < 8; i++) u.h[i] = f2bf(s[i]);
    *(uint4*)(wrt + ((size_t)(ks * 256 + o) * 32 + j0)) = u.v;
  } else {                                   // w_span: [ks][mt][phys][32], phys=k2*16+g
    int c16 = id - 8192;                     // < 73728
    int j0  = (c16 & 3) * 8;
    int row = c16 >> 2;                      // < 18432
    int phys = row % 144;
    int mtks = row / 144;                    // ks*16 + mt
    int mt = mtks & 15, ks = mtks >> 4;
    int g = phys & 15, k2 = phys >> 4;
    int sg = mt * 144 + g * 9 + k2;          // s = (mt*16+g)*9 + k2
    const float* s = wsp + (size_t)sg * 256 + ks * 32 + j0;
    #pragma unroll
    for (int i = 0; i < 8; i++) u.h[i] = f2bf(s[i]);
    *(uint4*)(wspt + ((size_t)row * 32 + j0)) = u.v;
  }
}

// ---------------- kernel 1: Wr = w_reduce @ X + b_reduce (bf16 out, tiled) ----------------
__global__ __launch_bounds__(256) void k1_reduce_gemm(
    const float* __restrict__ X, const uint16_t* __restrict__ wrt,
    const float* __restrict__ bred, uint16_t* __restrict__ Wr){
  const int pt = blockIdx.x, mt = blockIdx.y, b = blockIdx.z;
  const int p0 = pt * 128, o0 = mt * 128;
  __shared__ __align__(16) uint16_t Al[2][128*32];
  __shared__ __align__(16) uint16_t Bl[2][128*32];
  const int t = threadIdx.x;
  const int wv = t >> 6, lane = t & 63, q = lane >> 4, l = lane & 15;
  const int wm = wv >> 1, wn = wv & 1;
  const int c2 = (t & 15) * 2, seg = t >> 4;
  f32x4 acc[4][4] = {};
  union { float f[8]; float4 v[2]; } v0, v1;

  auto stageA = [&](int ks, int buf){
    const char* src = (const char*)(wrt + ((size_t)ks * 256 + o0) * 32);
    char* dst = (char*)(&Al[buf][0]);
    for (int cc = wv; cc < 8; cc += 4)
      glds16(src + cc*1024 + lane*16, dst + cc*1024);
  };
  auto loadB = [&](int ks){
    const float* s0 = X + ((size_t)(b * 256 + ks * 32 + c2)) * 4096 + p0 + seg * 8;
    const float* s1 = s0 + 4096;
    v0.v[0] = *(const float4*)(s0 + 0);
    v0.v[1] = *(const float4*)(s0 + 4);
    v1.v[0] = *(const float4*)(s1 + 0);
    v1.v[1] = *(const float4*)(s1 + 4);
  };
  auto writeB = [&](int buf){
    uint16_t* dst = &Bl[buf][(seg * 8) * 32 + c2];
    #pragma unroll
    for (int i = 0; i < 8; i++){
      uint32_t pk = (uint32_t)f2bf(v0.f[i]) | ((uint32_t)f2bf(v1.f[i]) << 16);
      *(uint32_t*)(dst + (size_t)i * 32) = pk;
    }
  };

  stageA(0, 0); loadB(0); writeB(0);
  __syncthreads();
  int cur = 0;
  for (int ks = 0; ks < 8; ks++){
    if (ks < 7){ stageA(ks + 1, cur ^ 1); loadB(ks + 1); }
    s16x8 af[4], bfv[4];
    #pragma unroll
    for (int mi = 0; mi < 4; mi++)
      af[mi] = *(const s16x8*)(&Al[cur][(wm*64 + mi*16 + l)*32 + q*8]);
    #pragma unroll
    for (int ni = 0; ni < 4; ni++)
      bfv[ni] = *(const s16x8*)(&Bl[cur][(wn*64 + ni*16 + l)*32 + q*8]);
    #pragma unroll
    for (int mi = 0; mi < 4; mi++)
      #pragma unroll
      for (int ni = 0; ni < 4; ni++)
        acc[mi][ni] = mfma16x16x32(af[mi], bfv[ni], acc[mi][ni], 0);
    if (ks < 7) writeB(cur ^ 1);
    __syncthreads();
    cur ^= 1;
  }
  // epilogue: +b_reduce, bf16, store tiled [b][o/32][p][o%32]
  #pragma unroll
  for (int mi = 0; mi < 4; mi++){
    int o = o0 + wm*64 + mi*16 + q*4;
    float4 br = *(const float4*)(bred + o);
    int slab = o >> 5, orem = o & 31;
    #pragma unroll
    for (int ni = 0; ni < 4; ni++){
      int p = p0 + wn*64 + ni*16 + l;
      f32x4 v = acc[mi][ni];
      uint32_t lo = (uint32_t)f2bf(v[0] + br.x) | ((uint32_t)f2bf(v[1] + br.y) << 16);
      uint32_t hi = (uint32_t)f2bf(v[2] + br.z) | ((uint32_t)f2bf(v[3] + br.w) << 16);
      uint2 pk; pk.x = lo; pk.y = hi;
      *(uint2*)(Wr + ((size_t)((b*8 + slab)*4096 + p)) * 32 + orem) = pk;
    }
  }
}

// ---------------- kernel 2a: per-channel partial sums (deterministic) ----------------
__global__ __launch_bounds__(256) void bn_stats(const uint16_t* __restrict__ Wr,
                                                float* __restrict__ part){
  const int s = blockIdx.y, k = blockIdx.x, t = threadIdx.x;
  const int j = t & 31, gsub = t >> 5;
  float sum = 0.f, sq = 0.f;
  const int rbase = k * 1024 + gsub;
  for (int i = 0; i < 128; i++){
    int r = rbase + i * 8;                 // r in [0,65536): (b=r>>12, p=r&4095)
    int bb = r >> 12, p = r & 4095;
    float v = bf2f(Wr[((size_t)((bb * 8 + s) * 4096) + p) * 32 + j]);
    sum += v; sq += v * v;
  }
  __shared__ float ls[8][32][2];
  ls[gsub][j][0] = sum; ls[gsub][j][1] = sq;
  __syncthreads();
  if (t < 32){
    float a = 0.f, b2 = 0.f;
    for (int g2 = 0; g2 < 8; g2++){ a += ls[g2][t][0]; b2 += ls[g2][t][1]; }
    float* dst = part + ((size_t)(s * 64 + k) * 32 + t) * 2;
    dst[0] = a; dst[1] = b2;
  }
}

// ---------------- kernel 2b: finalize BN coeffs ----------------
__global__ void bn_final(const float* __restrict__ part, const float* __restrict__ gamma,
                         const float* __restrict__ beta, float* __restrict__ coeffs){
  int c = threadIdx.x;
  int s = c >> 5, j = c & 31;
  float sum = 0.f, sq = 0.f;
  for (int k = 0; k < 64; k++){
    const float* p = part + ((size_t)(s * 64 + k) * 32 + j) * 2;
    sum += p[0]; sq += p[1];
  }
  const float inv = 1.0f / 65536.0f;
  float mean = sum * inv;
  float var  = sq * inv - mean * mean;
  float rstd = rsqrtf(var + 1e-5f);
  float A = gamma[c] * rstd;
  float Bc = beta[c] - mean * A;
  coeffs[2*c] = A; coeffs[2*c+1] = Bc;
}

// ---------------- kernel 2c: Wn = relu(Wr*A + B) in-place ----------------
// Wr = 2^25 B = 2,097,152 16B-chunks. 1024 blocks x 256 thr x 8 iters = exact cover.
__global__ __launch_bounds__(256) void bn_apply(uint16_t* __restrict__ Wr,
                                                const float* __restrict__ coeffs){
  __shared__ float cf[512];
  cf[threadIdx.x]       = coeffs[threadIdx.x];
  cf[threadIdx.x + 256] = coeffs[threadIdx.x + 256];
  __syncthreads();
  for (int it = 0; it < 8; it++){
    size_t c16 = (size_t)blockIdx.x * 256 + threadIdx.x + (size_t)it * (1024u*256u);
    uint16_t* pch = Wr + c16 * 8;
    int sj = (int)((c16 >> 14) & 7);       // slab (16384 chunks per (b,s))
    int j0 = (int)(c16 & 3) * 8;
    union { uint4 v; uint16_t h[8]; } u;
    u.v = *(const uint4*)pch;
    #pragma unroll
    for (int i = 0; i < 8; i++){
      int cch = sj * 32 + j0 + i;
      float v = bf2f(u.h[i]);
      v = fmaf(v, cf[2*cch], cf[2*cch+1]);
      v = fmaxf(v, 0.f);
      u.h[i] = f2bf(v);
    }
    *(uint4*)pch = u.v;
  }
}

// ---------------- kernel 3 v2: Ker = w_span @ Wn + b_span, fused involution ----------------
// 512 threads (8 waves). BM=144 (16 groups x 9 taps, phys=k2*16+g), BN=256.
// Wave w owns cols w*32..w*32+31 -> acc[9][2] = 72 VGPR. 2 blocks/CU target.
// T4: counted vmcnt (5 for A-staging waves 0-2, else 2), raw barriers.
// T2: XOR 16B-slot swizzle c ^= (row>>1)&3, applied on the GLOBAL source
//     (LDS dest linear for global_load_lds) and on the ds_read slot.
__global__ __launch_bounds__(512, 4) void k3_span_inv(
    const uint16_t* __restrict__ Wn, const uint16_t* __restrict__ wspt,
    const float* __restrict__ bspan, const float* __restrict__ X,
    float* __restrict__ out){
  const int mt = blockIdx.x, pt = blockIdx.y, b = blockIdx.z;
  const int p0 = pt * 256;
  __shared__ __align__(16) uint16_t Al[2][144*32];
  __shared__ __align__(16) uint16_t Bl[2][256*32];
  __shared__ float bsp[144];
  const int t = threadIdx.x;
  const int wv = t >> 6, lane = t & 63, q = lane >> 4, l = lane & 15;
  const int qs = q ^ ((l >> 1) & 3);        // swizzled 16B slot for frag reads
  if (t < 144){
    int g = t & 15, k2 = t >> 4;
    bsp[t] = bspan[mt*144 + g*9 + k2];      // indexed by phys
  }
  f32x4 acc[9][2] = {};

  // per-lane swizzled global offset within each 1KB (16-row) chunk:
  // lane i covers LDS row cc*16+(i>>2), slot i&3; source slot = (i&3)^((i>>3)&3)
  const int lsw = ((lane >> 2) << 6) + ((((lane & 3) ^ ((lane >> 3) & 3))) << 4);
  const char* Abase = (const char*)(wspt + (size_t)mt * (144*32));
  const size_t AslabB = (size_t)16 * 144 * 64;            // bytes per ks slab
  const char* Bbase = (const char*)(Wn + ((size_t)(b * 8) * 4096 + p0) * 32);
  const size_t BslabB = (size_t)4096 * 64;

  auto stage = [&](int ks, int buf){
    // B: all 8 waves, 2 chunks each (16 x 1KB total)
    const char* bsrc = Bbase + (size_t)ks * BslabB + (size_t)(wv*2) * 1024 + lsw;
    char* bdst = (char*)(&Bl[buf][0]) + (wv*2) * 1024;
    glds16(bsrc, bdst);
    glds16(bsrc + 1024, bdst + 1024);
    // A: waves 0-2, 3 chunks each (9 x 1KB total)
    if (wv < 3){
      const char* asrc = Abase + (size_t)ks * AslabB + (size_t)(wv*3) * 1024 + lsw;
      char* adst = (char*)(&Al[buf][0]) + (wv*3) * 1024;
      glds16(asrc, adst);
      glds16(asrc + 1024, adst + 1024);
      glds16(asrc + 2048, adst + 2048);
    }
  };

  stage(0, 0);
  int cur = 0;
  for (int ks = 0; ks < 8; ks++){
    if (ks < 7){
      stage(ks + 1, cur ^ 1);
      if (wv < 3) { WAITV(5); } else { WAITV(2); }   // wait prev stage only
    } else {
      WAITV(0);
    }
    BAR();
    s16x8 bfv[2];
    bfv[0] = *(const s16x8*)(&Bl[cur][(wv*32 +  0 + l)*32 + qs*8]);
    bfv[1] = *(const s16x8*)(&Bl[cur][(wv*32 + 16 + l)*32 + qs*8]);
    #pragma unroll
    for (int mi = 0; mi < 9; mi++){
      s16x8 af = *(const s16x8*)(&Al[cur][(mi*16 + l)*32 + qs*8]);
      acc[mi][0] = mfma16x16x32(af, bfv[0], acc[mi][0], 0);
      acc[mi][1] = mfma16x16x32(af, bfv[1], acc[mi][1], 0);
    }
    WAITL0;          // all my ds_reads complete before others may overwrite
    BAR();
    cur ^= 1;
  }
  // involution epilogue: out[g][p] = sum_k2 (Ker + b_span) * Xpatch
  const int h = pt*4 + (wv >> 1);
  const int wbase = (wv & 1) * 32;
  #pragma unroll
  for (int reg = 0; reg < 4; reg++){
    const int g  = q*4 + reg;
    const int gg = mt*16 + g;
    const float* Xc = X + (size_t)(b*256 + gg) * 4096;
    float* Oc = out + ((size_t)(b*256 + gg) * 64 + h) * 64;
    #pragma unroll
    for (int ni = 0; ni < 2; ni++){
      const int wc = wbase + ni*16 + l;
      float r = 0.f;
      #pragma unroll
      for (int k2 = 0; k2 < 9; k2++){
        const int dh = k2/3 - 1, dw = k2%3 - 1;
        const int hh = h + dh, ww = wc + dw;
        float xv = (hh >= 0 && hh < 64 && ww >= 0 && ww < 64) ? Xc[hh*64 + ww] : 0.f;
        r += (acc[k2][ni][reg] + bsp[k2*16 + g]) * xv;
      }
      Oc[wc] = r;
    }
  }
}

extern "C" void kernel_launch(void* const* d_in, const int* in_sizes, int n_in,
                              void* d_out, int out_size, void* d_ws, size_t ws_size,
                              hipStream_t stream) {
  const float* X     = (const float*)d_in[0];
  const float* wred  = (const float*)d_in[1];
  const float* bred  = (const float*)d_in[2];
  const float* gamma = (const float*)d_in[3];
  const float* beta  = (const float*)d_in[4];
  const float* wsp   = (const float*)d_in[5];
  const float* bsp   = (const float*)d_in[6];
  float* out = (float*)d_out;

  char* ws = (char*)d_ws;
  uint16_t* Wr   = (uint16_t*)(ws);
  uint16_t* wrt  = (uint16_t*)(ws + 33554432);
  uint16_t* wspt = (uint16_t*)(ws + 33554432 + 131072);
  float* part    = (float*)(ws + 33554432 + 131072 + 1179648);
  float* coeffs  = (float*)(ws + 33554432 + 131072 + 1179648 + 131072);
  if (ws_size < (size_t)(33554432 + 131072 + 1179648 + 131072 + 2048)) return;

  prep_weights<<<320, 256, 0, stream>>>(wred, wsp, wrt, wspt);
  k1_reduce_gemm<<<dim3(32, 2, 16), 256, 0, stream>>>(X, wrt, bred, Wr);
  bn_stats<<<dim3(64, 8), 256, 0, stream>>>(Wr, part);
  bn_final<<<1, 256, 0, stream>>>(part, gamma, beta, coeffs);
  bn_apply<<<1024, 256, 0, stream>>>(Wr, coeffs);
  k3_span_inv<<<dim3(16, 16, 16), 512, 0, stream>>>(Wr, wspt, bsp, X, out);
}

// Round 4
// 180.042 us; speedup vs baseline: 1.7628x; 1.0398x over previous
//
#include <hip/hip_runtime.h>
#include <stdint.h>

// Inv2d fused pipeline, MI355X gfx950.
// B=16, C=256, H=W=64, K2=9. All inputs fp32; internal GEMMs in bf16 MFMA.
//
// Pipeline: prep -> k1 (GEMM1 + fused BN partial stats) -> bn_final -> k3
// (GEMM2 with BN+ReLU applied on-the-fly to the B operand + fused involution).
//
// ws layout:
//   Wr raw (bf16, tiled [b][slab=c/32][p][c%32])  : 33,554,432 B
//   w_reduce bf16 tiled [ks][o][32]               :    131,072 B
//   w_span  bf16 tiled [ks][mt][phys=k2*16+g][32] :  1,179,648 B
//   part [c][512][2] f32 partial sums             :  1,048,576 B
//   coeffs [c][2] f32 (A=gamma*rstd, B=beta-mean*A):      2,048 B
//   total: 35,915,776 B

typedef __attribute__((ext_vector_type(4))) float f32x4;
typedef __attribute__((ext_vector_type(8))) short s16x8;
typedef __attribute__((ext_vector_type(8))) __bf16 bf16x8;

#define WAITV(N) asm volatile("s_waitcnt vmcnt(" #N ")" ::: "memory")
#define WAITL0   asm volatile("s_waitcnt lgkmcnt(0)" ::: "memory")
#define PIN()    asm volatile("" ::: "memory")
#define BAR()    do { PIN(); __builtin_amdgcn_s_barrier(); PIN(); } while (0)

__device__ __forceinline__ float bf2f(uint16_t u){
  union { uint32_t i; float f; } v; v.i = ((uint32_t)u) << 16; return v.f;
}
__device__ __forceinline__ uint16_t f2bf(float f){
  union { float f; uint32_t i; } v; v.f = f;
  return (uint16_t)((v.i + 0x7fffu + ((v.i >> 16) & 1u)) >> 16);  // RNE
}

// SFINAE shim: prefer short8 operands (guide-verified); fall back to __bf16 vec.
template <typename V>
__device__ __forceinline__ auto mfma16x16x32(V a, V b, f32x4 c, int)
    -> decltype(__builtin_amdgcn_mfma_f32_16x16x32_bf16(a, b, c, 0, 0, 0)) {
  return __builtin_amdgcn_mfma_f32_16x16x32_bf16(a, b, c, 0, 0, 0);
}
template <typename V>
__device__ __forceinline__ f32x4 mfma16x16x32(V a, V b, f32x4 c, long) {
  bf16x8 aa = __builtin_bit_cast(bf16x8, a);
  bf16x8 bb = __builtin_bit_cast(bf16x8, b);
  return __builtin_amdgcn_mfma_f32_16x16x32_bf16(aa, bb, c, 0, 0, 0);
}

typedef uint32_t u32_g __attribute__((address_space(1)));
typedef uint32_t u32_l __attribute__((address_space(3)));
__device__ __forceinline__ void glds16(const void* g, void* l){
  __builtin_amdgcn_global_load_lds((const u32_g*)g, (u32_l*)l, 16, 0, 0);
}

// ---------------- kernel 0: weight convert + pre-tile ----------------
__global__ __launch_bounds__(256) void prep_weights(
    const float* __restrict__ wred, const float* __restrict__ wsp,
    uint16_t* __restrict__ wrt, uint16_t* __restrict__ wspt){
  int id = blockIdx.x * 256 + threadIdx.x;   // 16B-chunk id, 320*256 = 81920 total
  union { uint4 v; uint16_t h[8]; } u;
  if (id < 8192){                            // w_reduce: [ks][o][32]
    int ks = id >> 10;
    int o  = (id >> 2) & 255;
    int j0 = (id & 3) * 8;
    const float* s = wred + o * 256 + ks * 32 + j0;
    #pragma unroll
    for (int i = 0; i < 8; i++) u.h[i] = f2bf(s[i]);
    *(uint4*)(wrt + ((size_t)(ks * 256 + o) * 32 + j0)) = u.v;
  } else {                                   // w_span: [ks][mt][phys][32], phys=k2*16+g
    int c16 = id - 8192;                     // < 73728
    int j0  = (c16 & 3) * 8;
    int row = c16 >> 2;                      // < 18432
    int phys = row % 144;
    int mtks = row / 144;                    // ks*16 + mt
    int mt = mtks & 15, ks = mtks >> 4;
    int g = phys & 15, k2 = phys >> 4;
    int sg = mt * 144 + g * 9 + k2;          // s = (mt*16+g)*9 + k2
    const float* s = wsp + (size_t)sg * 256 + ks * 32 + j0;
    #pragma unroll
    for (int i = 0; i < 8; i++) u.h[i] = f2bf(s[i]);
    *(uint4*)(wspt + ((size_t)row * 32 + j0)) = u.v;
  }
}

// ---------------- kernel 1: Wr = w_reduce @ X + b_reduce, + fused BN partials ----------------
__global__ __launch_bounds__(256) void k1_reduce_gemm(
    const float* __restrict__ X, const uint16_t* __restrict__ wrt,
    const float* __restrict__ bred, uint16_t* __restrict__ Wr,
    float* __restrict__ part){
  const int pt = blockIdx.x, mt = blockIdx.y, b = blockIdx.z;
  const int p0 = pt * 128, o0 = mt * 128;
  __shared__ __align__(16) uint16_t Al[2][128*32];
  __shared__ __align__(16) uint16_t Bl[2][128*32];
  __shared__ float redS[256], redQ[256];
  const int t = threadIdx.x;
  const int wv = t >> 6, lane = t & 63, q = lane >> 4, l = lane & 15;
  const int wm = wv >> 1, wn = wv & 1;
  const int c2 = (t & 15) * 2, seg = t >> 4;
  f32x4 acc[4][4] = {};
  union { float f[8]; float4 v[2]; } v0, v1;

  auto stageA = [&](int ks, int buf){
    const char* src = (const char*)(wrt + ((size_t)ks * 256 + o0) * 32);
    char* dst = (char*)(&Al[buf][0]);
    for (int cc = wv; cc < 8; cc += 4)
      glds16(src + cc*1024 + lane*16, dst + cc*1024);
  };
  auto loadB = [&](int ks){
    const float* s0 = X + ((size_t)(b * 256 + ks * 32 + c2)) * 4096 + p0 + seg * 8;
    const float* s1 = s0 + 4096;
    v0.v[0] = *(const float4*)(s0 + 0);
    v0.v[1] = *(const float4*)(s0 + 4);
    v1.v[0] = *(const float4*)(s1 + 0);
    v1.v[1] = *(const float4*)(s1 + 4);
  };
  auto writeB = [&](int buf){
    uint16_t* dst = &Bl[buf][(seg * 8) * 32 + c2];
    #pragma unroll
    for (int i = 0; i < 8; i++){
      uint32_t pk = (uint32_t)f2bf(v0.f[i]) | ((uint32_t)f2bf(v1.f[i]) << 16);
      *(uint32_t*)(dst + (size_t)i * 32) = pk;
    }
  };

  stageA(0, 0); loadB(0); writeB(0);
  __syncthreads();
  int cur = 0;
  for (int ks = 0; ks < 8; ks++){
    if (ks < 7){ stageA(ks + 1, cur ^ 1); loadB(ks + 1); }
    s16x8 af[4], bfv[4];
    #pragma unroll
    for (int mi = 0; mi < 4; mi++)
      af[mi] = *(const s16x8*)(&Al[cur][(wm*64 + mi*16 + l)*32 + q*8]);
    #pragma unroll
    for (int ni = 0; ni < 4; ni++)
      bfv[ni] = *(const s16x8*)(&Bl[cur][(wn*64 + ni*16 + l)*32 + q*8]);
    #pragma unroll
    for (int mi = 0; mi < 4; mi++)
      #pragma unroll
      for (int ni = 0; ni < 4; ni++)
        acc[mi][ni] = mfma16x16x32(af[mi], bfv[ni], acc[mi][ni], 0);
    if (ks < 7) writeB(cur ^ 1);
    __syncthreads();
    cur ^= 1;
  }
  // epilogue: +b_reduce, bf16 store (tiled), and per-channel partial sums
  float ssum[4][4] = {}, ssq[4][4] = {};
  #pragma unroll
  for (int mi = 0; mi < 4; mi++){
    int o = o0 + wm*64 + mi*16 + q*4;
    float4 br = *(const float4*)(bred + o);
    int slab = o >> 5, orem = o & 31;
    #pragma unroll
    for (int ni = 0; ni < 4; ni++){
      int p = p0 + wn*64 + ni*16 + l;
      f32x4 v = acc[mi][ni];
      float e0 = v[0] + br.x, e1 = v[1] + br.y, e2 = v[2] + br.z, e3 = v[3] + br.w;
      ssum[mi][0] += e0; ssq[mi][0] += e0*e0;
      ssum[mi][1] += e1; ssq[mi][1] += e1*e1;
      ssum[mi][2] += e2; ssq[mi][2] += e2*e2;
      ssum[mi][3] += e3; ssq[mi][3] += e3*e3;
      uint32_t lo = (uint32_t)f2bf(e0) | ((uint32_t)f2bf(e1) << 16);
      uint32_t hi = (uint32_t)f2bf(e2) | ((uint32_t)f2bf(e3) << 16);
      uint2 pk; pk.x = lo; pk.y = hi;
      *(uint2*)(Wr + ((size_t)((b*8 + slab)*4096 + p)) * 32 + orem) = pk;
    }
  }
  // reduce over the 16 l-lanes (within q-group)
  #pragma unroll
  for (int mi = 0; mi < 4; mi++)
    #pragma unroll
    for (int j = 0; j < 4; j++){
      #pragma unroll
      for (int off = 1; off < 16; off <<= 1){
        ssum[mi][j] += __shfl_xor(ssum[mi][j], off);
        ssq[mi][j]  += __shfl_xor(ssq[mi][j],  off);
      }
    }
  if (l == 0){
    #pragma unroll
    for (int mi = 0; mi < 4; mi++)
      #pragma unroll
      for (int j = 0; j < 4; j++){
        int ch_local = wm*64 + mi*16 + q*4 + j;   // [0,128)
        redS[ch_local*2 + wn] = ssum[mi][j];
        redQ[ch_local*2 + wn] = ssq[mi][j];
      }
  }
  __syncthreads();
  {
    int ch_local = t >> 1, m = t & 1;
    float val = m ? (redQ[ch_local*2] + redQ[ch_local*2+1])
                  : (redS[ch_local*2] + redS[ch_local*2+1]);
    int ch = o0 + ch_local;
    int idx = pt*16 + b;                         // [0,512)
    part[((size_t)ch*512 + idx)*2 + m] = val;
  }
}

// ---------------- kernel 2: finalize BN coeffs ----------------
__global__ __launch_bounds__(64) void bn_final(
    const float* __restrict__ part, const float* __restrict__ gamma,
    const float* __restrict__ beta, float* __restrict__ coeffs){
  int c = blockIdx.x, t = threadIdx.x;
  float s = 0.f, sq = 0.f;
  const float* p = part + (size_t)c * 1024;
  #pragma unroll
  for (int i = 0; i < 8; i++){
    float2 v = *(const float2*)(p + (t*8 + i)*2);
    s += v.x; sq += v.y;
  }
  #pragma unroll
  for (int off = 1; off < 64; off <<= 1){
    s  += __shfl_xor(s,  off);
    sq += __shfl_xor(sq, off);
  }
  if (t == 0){
    const float inv = 1.0f / 65536.0f;
    float mean = s * inv;
    float var  = sq * inv - mean * mean;
    float rstd = rsqrtf(var + 1e-5f);
    float A = gamma[c] * rstd;
    float Bc = beta[c] - mean * A;
    coeffs[2*c] = A; coeffs[2*c+1] = Bc;
  }
}

// ---------------- kernel 3 v3: Ker = w_span @ relu(A*Wr+B) + b_span, fused involution ----------------
// 256 threads (4 waves). BM=144 (phys=k2*16+g), BN=256 (4 h-rows). Wave wv owns
// h-row pt*4+wv (64 cols, ni=0..3). acc[9][4] = 144 VGPR. A via LDS (glds,
// both-sides 16B-slot swizzle); B global->reg (cols are wave-exclusive;
// Wr layout makes the fragment a coalesced dwordx4), BN+ReLU applied in VALU.
// One barrier per K-step; counted vmcnt (4) mid-loop.
__global__ __launch_bounds__(256, 2) void k3_span_inv(
    const uint16_t* __restrict__ Wr, const uint16_t* __restrict__ wspt,
    const float* __restrict__ bspan, const float* __restrict__ coeffs,
    const float* __restrict__ X, float* __restrict__ out){
  const int mt = blockIdx.x, pt = blockIdx.y, b = blockIdx.z;
  const int p0 = pt * 256;
  __shared__ __align__(16) uint16_t Al[2][144*32];
  __shared__ float cfA[256], cfB[256], bsp[144];
  const int t = threadIdx.x;
  const int wv = t >> 6, lane = t & 63, q = lane >> 4, l = lane & 15;
  const int qs = q ^ ((l >> 1) & 3);        // swizzled 16B slot for frag reads
  {
    float2 cf2 = *(const float2*)(coeffs + 2*t);
    cfA[t] = cf2.x; cfB[t] = cf2.y;
  }
  if (t < 144){
    int g = t & 15, k2 = t >> 4;
    bsp[t] = bspan[mt*144 + g*9 + k2];      // indexed by phys
  }
  f32x4 acc[9][4] = {};

  // per-lane swizzled global offset within each 1KB (16-row) chunk
  const int lsw = ((lane >> 2) << 6) + ((((lane & 3) ^ ((lane >> 3) & 3))) << 4);
  const char* Abase = (const char*)(wspt + (size_t)mt * (144*32));
  const size_t AslabB = (size_t)16 * 144 * 64;
  // B fragment base: p = p0 + wv*64 + ni*16 + l, k-slot q
  const uint16_t* Bb = Wr + (((size_t)(b*8))*4096 + p0 + wv*64 + l)*32 + q*8;
  const size_t BslabE = (size_t)4096 * 32;  // elements per ks slab

  auto stageA = [&](int ks, int buf){
    const char* asrc = Abase + (size_t)ks * AslabB + lsw;
    char* adst = (char*)(&Al[buf][0]);
    #pragma unroll
    for (int cc = 0; cc < 3; cc++){
      int ch = wv + cc*4;
      if (ch < 9) glds16(asrc + ch*1024, adst + ch*1024);
    }
  };

  uint4 breg[2][4];
  // prologue: stage(0), load B(0), B(1); LDS init; drain stage(0) only.
  stageA(0, 0);
  PIN();
  #pragma unroll
  for (int ni = 0; ni < 4; ni++) breg[0][ni] = *(const uint4*)(Bb + 0*BslabE + ni*512);
  #pragma unroll
  for (int ni = 0; ni < 4; ni++) breg[1][ni] = *(const uint4*)(Bb + 1*BslabE + ni*512);
  PIN();
  WAITV(8);
  WAITL0;
  BAR();

  #pragma unroll
  for (int ks = 0; ks < 8; ks++){
    if (ks < 7) stageA(ks + 1, (ks + 1) & 1);
    PIN();
    // BN coeffs for this ks (channels ks*32 + q*8 .. +7)
    float4 a0 = *(const float4*)&cfA[ks*32 + q*8];
    float4 a1 = *(const float4*)&cfA[ks*32 + q*8 + 4];
    float4 b0 = *(const float4*)&cfB[ks*32 + q*8];
    float4 b1 = *(const float4*)&cfB[ks*32 + q*8 + 4];
    float Ac[8] = {a0.x,a0.y,a0.z,a0.w,a1.x,a1.y,a1.z,a1.w};
    float Bc[8] = {b0.x,b0.y,b0.z,b0.w,b1.x,b1.y,b1.z,b1.w};
    s16x8 bfv[4];
    #pragma unroll
    for (int ni = 0; ni < 4; ni++){
      union { uint4 v; uint16_t h[8]; } u; u.v = breg[ks & 1][ni];
      union { s16x8 s; __bf16 o[8]; } w;
      #pragma unroll
      for (int i = 0; i < 8; i++){
        float f = bf2f(u.h[i]);
        f = fmaxf(fmaf(f, Ac[i], Bc[i]), 0.f);
        w.o[i] = (__bf16)f;
      }
      bfv[ni] = w.s;
    }
    // prefetch B(ks+2) into the slot just freed
    if (ks < 6){
      #pragma unroll
      for (int ni = 0; ni < 4; ni++)
        breg[ks & 1][ni] = *(const uint4*)(Bb + (size_t)(ks+2)*BslabE + ni*512);
    }
    __builtin_amdgcn_s_setprio(1);
    #pragma unroll
    for (int mi = 0; mi < 9; mi++){
      s16x8 af = *(const s16x8*)(&Al[ks & 1][(mi*16 + l)*32 + qs*8]);
      acc[mi][0] = mfma16x16x32(af, bfv[0], acc[mi][0], 0);
      acc[mi][1] = mfma16x16x32(af, bfv[1], acc[mi][1], 0);
      acc[mi][2] = mfma16x16x32(af, bfv[2], acc[mi][2], 0);
      acc[mi][3] = mfma16x16x32(af, bfv[3], acc[mi][3], 0);
    }
    __builtin_amdgcn_s_setprio(0);
    if (ks < 6) { WAITV(4); } else { WAITV(0); }  // drain stage(ks+1), keep B-prefetch in flight
    WAITL0;
    BAR();
  }

  // involution epilogue: out[g][p] = sum_k2 (Ker + b_span) * Xpatch
  const int h = pt*4 + wv;                  // each wave owns one image row
  #pragma unroll
  for (int reg = 0; reg < 4; reg++){
    const int g  = q*4 + reg;
    const int gg = mt*16 + g;
    const float* Xc = X + (size_t)(b*256 + gg) * 4096;
    float* Oc = out + ((size_t)(b*256 + gg) * 64 + h) * 64;
    #pragma unroll
    for (int ni = 0; ni < 4; ni++){
      const int wc = ni*16 + l;
      float r = 0.f;
      #pragma unroll
      for (int k2 = 0; k2 < 9; k2++){
        const int dh = k2/3 - 1, dw = k2%3 - 1;
        const int hh = h + dh, ww = wc + dw;
        float xv = (hh >= 0 && hh < 64 && ww >= 0 && ww < 64) ? Xc[hh*64 + ww] : 0.f;
        r += (acc[k2][ni][reg] + bsp[k2*16 + g]) * xv;
      }
      Oc[wc] = r;
    }
  }
}

extern "C" void kernel_launch(void* const* d_in, const int* in_sizes, int n_in,
                              void* d_out, int out_size, void* d_ws, size_t ws_size,
                              hipStream_t stream) {
  const float* X     = (const float*)d_in[0];
  const float* wred  = (const float*)d_in[1];
  const float* bred  = (const float*)d_in[2];
  const float* gamma = (const float*)d_in[3];
  const float* beta  = (const float*)d_in[4];
  const float* wsp   = (const float*)d_in[5];
  const float* bsp   = (const float*)d_in[6];
  float* out = (float*)d_out;

  char* ws = (char*)d_ws;
  uint16_t* Wr   = (uint16_t*)(ws);
  uint16_t* wrt  = (uint16_t*)(ws + 33554432);
  uint16_t* wspt = (uint16_t*)(ws + 33554432 + 131072);
  float* part    = (float*)(ws + 33554432 + 131072 + 1179648);
  float* coeffs  = (float*)(ws + 33554432 + 131072 + 1179648 + 1048576);
  if (ws_size < (size_t)(33554432 + 131072 + 1179648 + 1048576 + 2048)) return;

  prep_weights<<<320, 256, 0, stream>>>(wred, wsp, wrt, wspt);
  k1_reduce_gemm<<<dim3(32, 2, 16), 256, 0, stream>>>(X, wrt, bred, Wr, part);
  bn_final<<<256, 64, 0, stream>>>(part, gamma, beta, coeffs);
  k3_span_inv<<<dim3(16, 16, 16), 256, 0, stream>>>(Wr, wspt, bsp, coeffs, X, out);
}